// Round 5
// baseline (3501.974 us; speedup 1.0000x reference)
//
#include <hip/hip_runtime.h>
#include <cstdint>
#include <cstddef>

#define TLEN 512
#define HD   1024

typedef short bf16x8 __attribute__((ext_vector_type(8)));
typedef float f32x4  __attribute__((ext_vector_type(4)));

#define MFMA(a, b, c) __builtin_amdgcn_mfma_f32_16x16x32_bf16((a), (b), (c), 0, 0, 0)

static __device__ __forceinline__ unsigned short f2bf(float v) {
    unsigned u = __float_as_uint(v);
    u += 0x7fffu + ((u >> 16) & 1u);          // round-to-nearest-even
    return (unsigned short)(u >> 16);
}
static __device__ __forceinline__ float bf2f(unsigned short s) {
    return __uint_as_float((unsigned)s << 16);
}

// L1-bypassing, L2-CACHED 16B h-load (sc0 only). Freshness is guaranteed by
// the per-XCD leader's buffer_inv each step: h publish stores bypass L2
// (sc0 sc1), so any parity-p line in this XCD's L2 predates the inv and is
// wiped before we read; post-inv misses fill from coherent L3.
// NO implicit wait — caller must s_waitcnt vmcnt(0) (+ sched_barrier) before use.
static __device__ __forceinline__ bf16x8 ld_h16_l2(const unsigned short* p) {
    bf16x8 r;
    asm volatile("global_load_dwordx4 %0, %1, off sc0"
                 : "=&v"(r) : "v"(p) : "memory");
    return r;
}

// Write-through store (past L2, to coherent L3). Drained by explicit vmcnt.
static __device__ __forceinline__ void st_bypass_u16(unsigned short* p, unsigned short v) {
    unsigned vv = v;
    asm volatile("global_store_short %0, %1, off sc0 sc1" :: "v"(p), "v"(vv) : "memory");
}
static __device__ __forceinline__ void st_bypass_u32(unsigned* p, unsigned v) {
    asm volatile("global_store_dword %0, %1, off sc0 sc1" :: "v"(p), "v"(v) : "memory");
}

// 256 blocks = 2 batch-groups x 128 col-groups.
// Block (bg, hcb): owns batches [bg*16, bg*16+16) x h-cols [hcb*8, hcb*8+8).
// ws layout: slots[256] u32 @0 | claim[8] u32 @1024 | flags @2048 (64B/XCD)
//            | @4096: hhi0[32K] hlo0[32K] hhi1[32K] hlo1[32K] (ushort)
__global__ __launch_bounds__(512, 2)
void lstm_persist(const float* __restrict__ x,
                  const float* __restrict__ W,
                  const float* __restrict__ bias,
                  float* __restrict__ out,
                  unsigned* __restrict__ slots,
                  unsigned short* __restrict__ hbase)
{
    const int tid  = threadIdx.x;
    const int cb   = blockIdx.x;
    const int bg   = cb >> 7;           // batch group: rows [bg*16, bg*16+16)
    const int hcb  = cb & 127;          // h-cols [hcb*8, hcb*8+8)
    const int wv   = tid >> 6;          // wave 0..7: K-slice of 128 (x) + 128 (h)
    const int lane = tid & 63;
    const int mn   = lane & 15;         // A: m (batch) / B: n (z-col within frag)
    const int q    = lane >> 4;         // k = q*8 + j within a K-32 tile

    __shared__ f32x4 red[8][2][64];     // 16 KB partials
    __shared__ float zsh[16][33];
    __shared__ float cls[16][8];        // persistent cell state
    __shared__ int   sh_xcc, sh_leader;

    // ---- one-time: discover physical XCD; elect one leader per XCD ----
    if (tid == 0) {
        unsigned xcc;
        asm volatile("s_getreg_b32 %0, hwreg(HW_REG_XCC_ID, 0, 4)" : "=s"(xcc));
        unsigned r = __hip_atomic_fetch_add(&slots[256 + xcc], 1u,
                         __ATOMIC_RELAXED, __HIP_MEMORY_SCOPE_AGENT);
        sh_xcc    = (int)xcc;
        sh_leader = (r == 0u) ? 1 : 0;
    }

    // ---- one-time: persistent W fragments (hi/lo bf16 split), register-resident.
    // frag 0: z-cols = gate(0,1)*1024 + hcb*8 + col;  frag 1: gates (2,3).
    const int zc0 = ((mn >> 3)    ) * 1024 + hcb * 8 + (mn & 7);
    const int zc1 = ((mn >> 3) + 2) * 1024 + hcb * 8 + (mn & 7);
    const int kx0 = wv * 128;

    bf16x8 wxh[4][2], wxl[4][2], whh[4][2], whl[4][2];
    #pragma unroll
    for (int kk = 0; kk < 4; ++kk) {
        #pragma unroll
        for (int j = 0; j < 8; ++j) {
            const int r = kx0 + kk * 32 + q * 8 + j;
            float v0 = W[(size_t)r * 4096 + zc0];
            unsigned short h0 = f2bf(v0);
            wxh[kk][0][j] = (short)h0;
            wxl[kk][0][j] = (short)f2bf(v0 - bf2f(h0));
            float v1 = W[(size_t)r * 4096 + zc1];
            unsigned short h1 = f2bf(v1);
            wxh[kk][1][j] = (short)h1;
            wxl[kk][1][j] = (short)f2bf(v1 - bf2f(h1));
            float u0 = W[(size_t)(1024 + r) * 4096 + zc0];
            unsigned short g0 = f2bf(u0);
            whh[kk][0][j] = (short)g0;
            whl[kk][0][j] = (short)f2bf(u0 - bf2f(g0));
            float u1 = W[(size_t)(1024 + r) * 4096 + zc1];
            unsigned short g1 = f2bf(u1);
            whh[kk][1][j] = (short)g1;
            whl[kk][1][j] = (short)f2bf(u1 - bf2f(g1));
        }
    }

    float bi = 0.f, bj = 0.f, bff = 0.f, bo = 0.f;
    if (tid < 128) {
        int b = tid >> 3, hc = tid & 7;
        int c0 = hcb * 8 + hc;
        bi  = bias[c0];
        bj  = bias[1024 + c0];
        bff = bias[2048 + c0];
        bo  = bias[3072 + c0];
        cls[b][hc] = 0.f;
    }
    __syncthreads();
    const bool leader = (sh_leader != 0);
    unsigned* flagp = slots + 512 + sh_xcc * 16;   // 64B-spaced per-XCD flag

    f32x4 acc0 = {0.f, 0.f, 0.f, 0.f};
    f32x4 acc1 = {0.f, 0.f, 0.f, 0.f};

    auto do_xpart = [&](int tt) {
        const size_t b0 = ((size_t)(bg * 16 + mn) * TLEN + tt) * HD + kx0 + q * 8;
        #pragma unroll
        for (int kk = 0; kk < 4; ++kk) {
            const float* p0 = x + b0 + kk * 32;
            f32x4 a0 = *(const f32x4*)(p0);
            f32x4 a1 = *(const f32x4*)(p0 + 4);
            bf16x8 xh, xl;
            #pragma unroll
            for (int j = 0; j < 4; ++j) {
                float vv; unsigned short h;
                vv = a0[j]; h = f2bf(vv); xh[j]     = (short)h; xl[j]     = (short)f2bf(vv - bf2f(h));
                vv = a1[j]; h = f2bf(vv); xh[4 + j] = (short)h; xl[4 + j] = (short)f2bf(vv - bf2f(h));
            }
            acc0 = MFMA(xh, wxh[kk][0], acc0);
            acc0 = MFMA(xl, wxh[kk][0], acc0);
            acc0 = MFMA(xh, wxl[kk][0], acc0);
            acc1 = MFMA(xh, wxh[kk][1], acc1);
            acc1 = MFMA(xl, wxh[kk][1], acc1);
            acc1 = MFMA(xh, wxl[kk][1], acc1);
        }
    };

    auto do_hpart = [&](const unsigned short* Hh, const unsigned short* Hl) {
        const int off = (bg * 16 + mn) * HD + kx0 + q * 8;
        bf16x8 ah[4], al[4];
        // issue all 8 x 16B L2-served loads back-to-back (fully pipelined),
        #pragma unroll
        for (int kk = 0; kk < 4; ++kk) {
            ah[kk] = ld_h16_l2(Hh + off + kk * 32);
            al[kk] = ld_h16_l2(Hl + off + kk * 32);
        }
        // ...then ONE drain; sched_barrier keeps MFMAs below the waitcnt (rule #18)
        asm volatile("s_waitcnt vmcnt(0)" ::: "memory");
        __builtin_amdgcn_sched_barrier(0);
        #pragma unroll
        for (int kk = 0; kk < 4; ++kk) {
            acc0 = MFMA(ah[kk], whh[kk][0], acc0);
            acc0 = MFMA(al[kk], whh[kk][0], acc0);
            acc0 = MFMA(ah[kk], whl[kk][0], acc0);
            acc1 = MFMA(ah[kk], whh[kk][1], acc1);
            acc1 = MFMA(al[kk], whh[kk][1], acc1);
            acc1 = MFMA(ah[kk], whl[kk][1], acc1);
        }
    };

    unsigned short* hhi0 = hbase;
    unsigned short* hlo0 = hbase + 32768;
    unsigned short* hhi1 = hbase + 65536;
    unsigned short* hlo1 = hbase + 98304;

    do_xpart(TLEN - 1);   // prefold x-part of step 0

    for (int t = 0; t < TLEN; ++t) {
        const unsigned short* Hh = (t & 1) ? hhi1 : hhi0;
        const unsigned short* Hl = (t & 1) ? hlo1 : hlo0;
        unsigned short* Ph = (t & 1) ? hhi0 : hhi1;
        unsigned short* Pl = (t & 1) ? hlo0 : hlo1;

        do_hpart(Hh, Hl);

        red[wv][0][lane] = acc0;
        red[wv][1][lane] = acc1;
        __syncthreads();
        if (tid < 128) {
            int frag = tid >> 6, l = tid & 63;
            f32x4 s = red[0][frag][l];
            #pragma unroll
            for (int w = 1; w < 8; ++w) s += red[w][frag][l];
            int nn = l & 15, qq = l >> 4;
            int m0 = qq * 4;
            zsh[m0 + 0][frag * 16 + nn] = s[0];
            zsh[m0 + 1][frag * 16 + nn] = s[1];
            zsh[m0 + 2][frag * 16 + nn] = s[2];
            zsh[m0 + 3][frag * 16 + nn] = s[3];
        }
        __syncthreads();
        if (tid < 128) {
            int b = tid >> 3, hc = tid & 7;
            float zi = zsh[b][hc]      + bi;
            float zj = zsh[b][8 + hc]  + bj;
            float zf = zsh[b][16 + hc] + bff;
            float zo = zsh[b][24 + hc] + bo;
            float co = cls[b][hc];
            float ig = 1.f / (1.f + expf(-zi));
            float fg = 1.f / (1.f + expf(-(zf + 1.0f)));   // forget bias = 1.0
            float og = 1.f / (1.f + expf(-zo));
            float jt = tanhf(zj);
            float cn = fg * co + ig * jt;
            float hn = og * tanhf(cn);
            cls[b][hc] = cn;
            unsigned short hh = f2bf(hn);
            unsigned short hl = f2bf(hn - bf2f(hh));
            int wi = (bg * 16 + b) * HD + hcb * 8 + hc;
            // order: h-hi, h-lo, out; vmcnt(1) drains the two h publishes
            // but leaves the (never-read) HBM out-store in flight.
            st_bypass_u16(Ph + wi, hh);
            st_bypass_u16(Pl + wi, hl);
            __builtin_nontemporal_store(cn,
                &out[((size_t)(bg * 16 + b) * TLEN + t) * HD + hcb * 8 + hc]);
            asm volatile("s_waitcnt vmcnt(1)" ::: "memory");
        }
        acc0 = (f32x4){0.f, 0.f, 0.f, 0.f};
        acc1 = (f32x4){0.f, 0.f, 0.f, 0.f};
        __syncthreads();   // all waves' h publishes are now drained to L3

        if (t + 1 < TLEN) {
            const unsigned tgt = (unsigned)(t + 1);
            if (tid == 0) {
                // store-based arrival: one monotonic 4B slot per block (no RMW).
                st_bypass_u32(&slots[cb], tgt);
                // LEADER ONLY: early agent-acquire (buffer_inv). Early inv can
                // never yield wrong data (publishes bypass L2; wiping fresh
                // lines only costs refetch) — so overlap it with the poll
                // window. It completes, in tid0 program order, before the
                // flag store below.
                if (leader) __builtin_amdgcn_fence(__ATOMIC_ACQUIRE, "agent");
            }
            // overlap wait with next step's x-part (h-independent; x is plain
            // cached + read-only, so a concurrent inv is refetch-only-safe)
            do_xpart(TLEN - 2 - t);
            if (leader) {
                // 8 leader blocks poll all 256 arrival slots (waves 0..3,
                // 1 dword/lane), then release their XCD via the flag.
                if (wv < 4) {
                    const unsigned* sp = &slots[(wv << 6) + lane];
                    while (__hip_atomic_load(sp, __ATOMIC_RELAXED,
                               __HIP_MEMORY_SCOPE_AGENT) < tgt) {
                        __builtin_amdgcn_s_sleep(1);
                    }
                }
                __syncthreads();
                if (tid == 0) st_bypass_u32(flagp, tgt);
            } else {
                // members: single-thread poll of this XCD's flag (L3-served).
                // flag >= tgt implies: all 256 publishes drained to L3 AND
                // this XCD's L2 was invalidated afterward.
                if (tid == 0) {
                    while (__hip_atomic_load(flagp, __ATOMIC_RELAXED,
                               __HIP_MEMORY_SCOPE_AGENT) < tgt) {
                        __builtin_amdgcn_s_sleep(1);
                    }
                }
            }
            __syncthreads();
        }
    }
}

extern "C" void kernel_launch(void* const* d_in, const int* in_sizes, int n_in,
                              void* d_out, int out_size, void* d_ws, size_t ws_size,
                              hipStream_t stream)
{
    (void)in_sizes; (void)n_in; (void)out_size; (void)ws_size;
    const float* x    = (const float*)d_in[0];
    // d_in[1] = sl (unused by reference)
    const float* W    = (const float*)d_in[2];
    const float* bias = (const float*)d_in[3];
    float* out = (float*)d_out;

    unsigned* slots = (unsigned*)d_ws;
    unsigned short* hbase = (unsigned short*)((char*)d_ws + 4096);

    // zero slots + claim counters + flags + h double-buffers; stream-ordered
    // memset is cache-coherent w.r.t. the following kernel (boundary flush)
    hipMemsetAsync(d_ws, 0, 4096 + 262144, stream);

    lstm_persist<<<256, 512, 0, stream>>>(x, W, bias, out, slots, hbase);
}

// Round 7
// 3028.806 us; speedup vs baseline: 1.1562x; 1.1562x over previous
//
#include <hip/hip_runtime.h>
#include <cstdint>
#include <cstddef>

#define TLEN 512
#define HD   1024

typedef short bf16x8 __attribute__((ext_vector_type(8)));
typedef float f32x4  __attribute__((ext_vector_type(4)));

#define MFMA(a, b, c) __builtin_amdgcn_mfma_f32_16x16x32_bf16((a), (b), (c), 0, 0, 0)

static __device__ __forceinline__ unsigned short f2bf(float v) {
    unsigned u = __float_as_uint(v);
    u += 0x7fffu + ((u >> 16) & 1u);          // round-to-nearest-even
    return (unsigned short)(u >> 16);
}
static __device__ __forceinline__ float bf2f(unsigned short s) {
    return __uint_as_float((unsigned)s << 16);
}

// Coherent (L1+L2-bypassing) 16B load for the publish region.
// NO implicit wait — caller must s_waitcnt vmcnt(0) (+ sched_barrier) before use.
static __device__ __forceinline__ bf16x8 ld_h16a(const unsigned short* p) {
    bf16x8 r;
    asm volatile("global_load_dwordx4 %0, %1, off sc0 sc1"
                 : "=&v"(r) : "v"(p) : "memory");
    return r;
}

// Write-through store (past L2, to coherent L3). Drained by explicit vmcnt.
static __device__ __forceinline__ void st_bypass_u16(unsigned short* p, unsigned short v) {
    unsigned vv = v;
    asm volatile("global_store_short %0, %1, off sc0 sc1" :: "v"(p), "v"(vv) : "memory");
}
static __device__ __forceinline__ void st_bypass_u32(unsigned* p, unsigned v) {
    asm volatile("global_store_dword %0, %1, off sc0 sc1" :: "v"(p), "v"(v) : "memory");
}

// 256 blocks = 2 batch-groups x 128 col-groups.
// Block (bg, hcb): owns batches [bg*16, bg*16+16) x h-cols [hcb*8, hcb*8+8).
//
// h path: publish (sc0 sc1, write-through to L3) -> per-step DENSE staged copy
// into LDS (line-coalesced bypass reads: each instr = 2x512B dense segments)
// -> MFMA fragments read LDS. This fixes the fragment-direct pattern (16 rows
// x 64B half-line segments per instr) that throttled L3 service.
//
// ws layout: slots[256] u32 @0 | @4096: hhi0[32K] hlo0[32K] hhi1[32K] hlo1[32K]
__global__ __launch_bounds__(512, 2)
void lstm_persist(const float* __restrict__ x,
                  const float* __restrict__ W,
                  const float* __restrict__ bias,
                  float* __restrict__ out,
                  unsigned* __restrict__ slots,
                  unsigned short* __restrict__ hbase)
{
    const int tid  = threadIdx.x;
    const int cb   = blockIdx.x;
    const int bg   = cb >> 7;           // batch group: rows [bg*16, bg*16+16)
    const int hcb  = cb & 127;          // h-cols [hcb*8, hcb*8+8)
    const int wv   = tid >> 6;          // wave 0..7: K-slice of 128 (x) + 128 (h)
    const int lane = tid & 63;
    const int mn   = lane & 15;         // A: m (batch) / B: n (z-col within frag)
    const int q    = lane >> 4;         // k = q*8 + j within a K-32 tile

    __shared__ f32x4 red[8][2][64];     // 16 KB partials
    __shared__ float zsh[16][33];
    __shared__ float cls[16][8];        // persistent cell state
    // staged h for the CURRENT step: rows = this bg's 16 batches, cols = 1024
    // (+8-short pad: fragment b128 reads land ~8-way conflicts, ~0.12us/step)
    __shared__ unsigned short lds_hh[16][1032];
    __shared__ unsigned short lds_hl[16][1032];

    // ---- one-time: persistent W fragments (hi/lo bf16 split), register-resident.
    // frag 0: z-cols = gate(0,1)*1024 + hcb*8 + col;  frag 1: gates (2,3).
    const int zc0 = ((mn >> 3)    ) * 1024 + hcb * 8 + (mn & 7);
    const int zc1 = ((mn >> 3) + 2) * 1024 + hcb * 8 + (mn & 7);
    const int kx0 = wv * 128;

    bf16x8 wxh[4][2], wxl[4][2], whh[4][2], whl[4][2];
    #pragma unroll
    for (int kk = 0; kk < 4; ++kk) {
        #pragma unroll
        for (int j = 0; j < 8; ++j) {
            const int r = kx0 + kk * 32 + q * 8 + j;
            float v0 = W[(size_t)r * 4096 + zc0];
            unsigned short h0 = f2bf(v0);
            wxh[kk][0][j] = (short)h0;
            wxl[kk][0][j] = (short)f2bf(v0 - bf2f(h0));
            float v1 = W[(size_t)r * 4096 + zc1];
            unsigned short h1 = f2bf(v1);
            wxh[kk][1][j] = (short)h1;
            wxl[kk][1][j] = (short)f2bf(v1 - bf2f(h1));
            float u0 = W[(size_t)(1024 + r) * 4096 + zc0];
            unsigned short g0 = f2bf(u0);
            whh[kk][0][j] = (short)g0;
            whl[kk][0][j] = (short)f2bf(u0 - bf2f(g0));
            float u1 = W[(size_t)(1024 + r) * 4096 + zc1];
            unsigned short g1 = f2bf(u1);
            whh[kk][1][j] = (short)g1;
            whl[kk][1][j] = (short)f2bf(u1 - bf2f(g1));
        }
    }

    float bi = 0.f, bj = 0.f, bff = 0.f, bo = 0.f;
    if (tid < 128) {
        int b = tid >> 3, hc = tid & 7;
        int c0 = hcb * 8 + hc;
        bi  = bias[c0];
        bj  = bias[1024 + c0];
        bff = bias[2048 + c0];
        bo  = bias[3072 + c0];
        cls[b][hc] = 0.f;
    }
    // zero the staged-h LDS (step 0 reads h = 0)
    {
        unsigned* lz = (unsigned*)&lds_hh[0][0];
        for (int i = tid; i < (int)(sizeof(lds_hh) + sizeof(lds_hl)) / 4; i += 512)
            lz[i] = 0u;
    }
    __syncthreads();

    f32x4 acc0 = {0.f, 0.f, 0.f, 0.f};
    f32x4 acc1 = {0.f, 0.f, 0.f, 0.f};

    auto do_xpart = [&](int tt) {
        const size_t b0 = ((size_t)(bg * 16 + mn) * TLEN + tt) * HD + kx0 + q * 8;
        #pragma unroll
        for (int kk = 0; kk < 4; ++kk) {
            const float* p0 = x + b0 + kk * 32;
            f32x4 a0 = *(const f32x4*)(p0);
            f32x4 a1 = *(const f32x4*)(p0 + 4);
            bf16x8 xh, xl;
            #pragma unroll
            for (int j = 0; j < 4; ++j) {
                float vv; unsigned short h;
                vv = a0[j]; h = f2bf(vv); xh[j]     = (short)h; xl[j]     = (short)f2bf(vv - bf2f(h));
                vv = a1[j]; h = f2bf(vv); xh[4 + j] = (short)h; xl[4 + j] = (short)f2bf(vv - bf2f(h));
            }
            acc0 = MFMA(xh, wxh[kk][0], acc0);
            acc0 = MFMA(xl, wxh[kk][0], acc0);
            acc0 = MFMA(xh, wxl[kk][0], acc0);
            acc1 = MFMA(xh, wxh[kk][1], acc1);
            acc1 = MFMA(xl, wxh[kk][1], acc1);
            acc1 = MFMA(xh, wxl[kk][1], acc1);
        }
    };

    // h-part reads the LDS-staged copy (values identical to round-4 path).
    auto do_hpart = [&]() {
        const int coff = kx0 + q * 8;
        bf16x8 ah[4], al[4];
        #pragma unroll
        for (int kk = 0; kk < 4; ++kk) {
            ah[kk] = *(const bf16x8*)&lds_hh[mn][coff + kk * 32];
            al[kk] = *(const bf16x8*)&lds_hl[mn][coff + kk * 32];
        }
        #pragma unroll
        for (int kk = 0; kk < 4; ++kk) {
            acc0 = MFMA(ah[kk], whh[kk][0], acc0);
            acc0 = MFMA(al[kk], whh[kk][0], acc0);
            acc0 = MFMA(ah[kk], whl[kk][0], acc0);
            acc1 = MFMA(ah[kk], whh[kk][1], acc1);
            acc1 = MFMA(al[kk], whh[kk][1], acc1);
            acc1 = MFMA(ah[kk], whl[kk][1], acc1);
        }
    };

    unsigned short* hhi0 = hbase;
    unsigned short* hlo0 = hbase + 32768;
    unsigned short* hhi1 = hbase + 65536;
    unsigned short* hlo1 = hbase + 98304;

    do_xpart(TLEN - 1);   // prefold x-part of step 0

    for (int t = 0; t < TLEN; ++t) {
        unsigned short* Ph = (t & 1) ? hhi0 : hhi1;
        unsigned short* Pl = (t & 1) ? hlo0 : hlo1;

        do_hpart();

        red[wv][0][lane] = acc0;
        red[wv][1][lane] = acc1;
        __syncthreads();
        if (tid < 128) {
            int frag = tid >> 6, l = tid & 63;
            f32x4 s = red[0][frag][l];
            #pragma unroll
            for (int w = 1; w < 8; ++w) s += red[w][frag][l];
            int nn = l & 15, qq = l >> 4;
            int m0 = qq * 4;
            zsh[m0 + 0][frag * 16 + nn] = s[0];
            zsh[m0 + 1][frag * 16 + nn] = s[1];
            zsh[m0 + 2][frag * 16 + nn] = s[2];
            zsh[m0 + 3][frag * 16 + nn] = s[3];
        }
        __syncthreads();
        if (tid < 128) {
            int b = tid >> 3, hc = tid & 7;
            float zi = zsh[b][hc]      + bi;
            float zj = zsh[b][8 + hc]  + bj;
            float zf = zsh[b][16 + hc] + bff;
            float zo = zsh[b][24 + hc] + bo;
            float co = cls[b][hc];
            float ig = 1.f / (1.f + expf(-zi));
            float fg = 1.f / (1.f + expf(-(zf + 1.0f)));   // forget bias = 1.0
            float og = 1.f / (1.f + expf(-zo));
            float jt = tanhf(zj);
            float cn = fg * co + ig * jt;
            float hn = og * tanhf(cn);
            cls[b][hc] = cn;
            unsigned short hh = f2bf(hn);
            unsigned short hl = f2bf(hn - bf2f(hh));
            int wi = (bg * 16 + b) * HD + hcb * 8 + hc;
            // order: h-hi, h-lo, out; vmcnt(1) drains the two h publishes
            // but leaves the (never-read) HBM out-store in flight.
            st_bypass_u16(Ph + wi, hh);
            st_bypass_u16(Pl + wi, hl);
            __builtin_nontemporal_store(cn,
                &out[((size_t)(bg * 16 + b) * TLEN + t) * HD + hcb * 8 + hc]);
            asm volatile("s_waitcnt vmcnt(1)" ::: "memory");
        }
        acc0 = (f32x4){0.f, 0.f, 0.f, 0.f};
        acc1 = (f32x4){0.f, 0.f, 0.f, 0.f};
        __syncthreads();   // all waves' h publishes are now drained to L3

        if (t + 1 < TLEN) {
            const unsigned tgt = (unsigned)(t + 1);
            // store-based arrival: one monotonic 4B slot per block (no RMW).
            if (tid == 0) st_bypass_u32(&slots[cb], tgt);
            // overlap arrival propagation with next step's x-part (h-independent)
            do_xpart(TLEN - 2 - t);
            // direct poll: waves 0..3 each watch 64 slots (1 dword/lane,
            // 4 coalesced lines/wave); no central release word.
            if (wv < 4) {
                const unsigned* sp = &slots[(wv << 6) + lane];
                while (__hip_atomic_load(sp, __ATOMIC_RELAXED,
                           __HIP_MEMORY_SCOPE_AGENT) < tgt) {
                    __builtin_amdgcn_s_sleep(1);
                }
            }
            __syncthreads();
            // ---- DENSE staged copy of next step's h into LDS ----
            // thread i -> row = i>>5 (16 rows), 16B chunk = i&31; 4 passes.
            // Per wave-instr: 2 rows x 512B fully-dense -> pure 128B-line
            // requests at L3 (vs 16x64B half-line segments fragment-direct).
            {
                const int row = tid >> 5;
                const int c0s = (tid & 31) * 8;          // shorts within row
                const unsigned short* Gh = Ph + (size_t)(bg * 16 + row) * HD;
                const unsigned short* Gl = Pl + (size_t)(bg * 16 + row) * HD;
                bf16x8 vh[4], vl[4];
                #pragma unroll
                for (int pp = 0; pp < 4; ++pp) {
                    vh[pp] = ld_h16a(Gh + pp * 256 + c0s);
                    vl[pp] = ld_h16a(Gl + pp * 256 + c0s);
                }
                asm volatile("s_waitcnt vmcnt(0)" ::: "memory");
                __builtin_amdgcn_sched_barrier(0);
                #pragma unroll
                for (int pp = 0; pp < 4; ++pp) {
                    *(bf16x8*)&lds_hh[row][pp * 256 + c0s] = vh[pp];
                    *(bf16x8*)&lds_hl[row][pp * 256 + c0s] = vl[pp];
                }
            }
            __syncthreads();   // staged h visible to all waves for step t+1
        }
    }
}

extern "C" void kernel_launch(void* const* d_in, const int* in_sizes, int n_in,
                              void* d_out, int out_size, void* d_ws, size_t ws_size,
                              hipStream_t stream)
{
    (void)in_sizes; (void)n_in; (void)out_size; (void)ws_size;
    const float* x    = (const float*)d_in[0];
    // d_in[1] = sl (unused by reference)
    const float* W    = (const float*)d_in[2];
    const float* bias = (const float*)d_in[3];
    float* out = (float*)d_out;

    unsigned* slots = (unsigned*)d_ws;
    unsigned short* hbase = (unsigned short*)((char*)d_ws + 4096);

    // zero arrival slots + h double-buffers; stream-ordered memset is
    // cache-coherent w.r.t. the following kernel (kernel-boundary flush)
    hipMemsetAsync(d_ws, 0, 4096 + 262144, stream);

    lstm_persist<<<256, 512, 0, stream>>>(x, W, bias, out, slots, hbase);
}